// Round 2
// baseline (651.698 us; speedup 1.0000x reference)
//
#include <hip/hip_runtime.h>
#include <math.h>

#define BB   4
#define CIN  64
#define CMID 32
#define HS   96
#define WS   96
#define H2   48
#define W2   48
#define H4   24
#define W4   24
#define N2   (H2*W2)   // 2304 distinct queries
#define M4   (H4*W4)   // 576 distinct keys

// ---------------------------------------------------------------------------
// K1a: 3x3 stride-2 pad-1 convs.
//  cz=0 (theta): block = 1 output row (48 cols x 32 co), full 64 ci.
//                grid.x = row 0..47.  Writes T[b][n][co] (+bias).
//  cz=1,2 (phi/phi_pan): block = 2 output rows, HALF the ci range.
//                grid.x = p*2+half.  Writes partial conv (no bias) to Pphi.
// All blocks: 256 thr, co = tid&31, g = tid>>5 (6 cols each), ~3456 FMA/thr.
// ---------------------------------------------------------------------------
__global__ __launch_bounds__(256) void conv3x3_kernel(
    const float* __restrict__ x, const float* __restrict__ x_pan,
    const float* __restrict__ theta_w, const float* __restrict__ theta_b,
    const float* __restrict__ phi_w, const float* __restrict__ phi_pan_w,
    float* __restrict__ T, float* __restrict__ Pphi)
{
    const int bx = blockIdx.x;   // 0..47
    const int b  = blockIdx.y;
    const int cz = blockIdx.z;   // 0 theta, 1 phi, 2 phi_pan

    __shared__ __align__(16) float xs[16][5][112];
    __shared__ float wsm[16][9][32];

    const int tid = threadIdx.x;
    const int co  = tid & 31;
    const int g   = tid >> 5;

    const float* xin = (cz == 2) ? x_pan : x;
    const float* wgt = (cz == 0) ? theta_w : (cz == 1 ? phi_w : phi_pan_w);

    if (cz == 0) {
        // ---- theta: single output row p, all 64 ci in chunks of 16 ----
        const int p = bx;
        const int row0 = 2*p - 1;
        float acc[6] = {0.f,0.f,0.f,0.f,0.f,0.f};

        for (int ci0 = 0; ci0 < 64; ci0 += 16) {
            __syncthreads();
            // stage x: 16ci x 3 rows x 28 float4 (pad cols are whole zero float4s)
            for (int u = tid; u < 16*3*28; u += 256) {
                int ci = u / 84, rem = u % 84, rr = rem / 28, k = rem % 28;
                int row = row0 + rr;
                float4 v = {0.f,0.f,0.f,0.f};
                if (row >= 0 && k >= 2 && k <= 25)
                    v = *(const float4*)&xin[((b*64 + ci0 + ci)*96 + row)*96 + 4*k - 8];
                *(float4*)&xs[ci][rr][4*k] = v;
            }
            // stage w chunk: contiguous float4 per co, scatter to [ci][kk][co]
            for (int u = tid; u < 1152; u += 256) {
                int c2 = u / 36, f = u % 36;
                float4 wv = *(const float4*)&wgt[c2*576 + ci0*9 + 4*f];
                int lin = 4*f;
                wsm[(lin  )/9][(lin  )%9][c2] = wv.x;
                wsm[(lin+1)/9][(lin+1)%9][c2] = wv.y;
                wsm[(lin+2)/9][(lin+2)%9][c2] = wv.z;
                wsm[(lin+3)/9][(lin+3)%9][c2] = wv.w;
            }
            __syncthreads();

            for (int ci = 0; ci < 16; ++ci) {
                float w9[9];
                #pragma unroll
                for (int kk = 0; kk < 9; ++kk) w9[kk] = wsm[ci][kk][co];
                #pragma unroll
                for (int rr = 0; rr < 3; ++rr) {
                    const float4* xr = (const float4*)&xs[ci][rr][12*g + 4];
                    float4 t0 = xr[0], t1 = xr[1], t2 = xr[2], t3 = xr[3];
                    float xv[16] = {t0.x,t0.y,t0.z,t0.w, t1.x,t1.y,t1.z,t1.w,
                                    t2.x,t2.y,t2.z,t2.w, t3.x,t3.y,t3.z,t3.w};
                    #pragma unroll
                    for (int j = 0; j < 6; ++j)
                        #pragma unroll
                        for (int kw = 0; kw < 3; ++kw)
                            acc[j] += w9[rr*3+kw] * xv[3 + 2*j + kw];
                }
            }
        }
        const float bv = theta_b[co];
        #pragma unroll
        for (int j = 0; j < 6; ++j)
            T[(b*N2 + p*48 + 6*g + j)*32 + co] = acc[j] + bv;   // [b][n][c]
    } else {
        // ---- phi: 2 output rows (pair p), half ci range, partial out ----
        const int p = bx >> 1, half = bx & 1;
        const int row0 = 4*p - 1;
        float acc[2][6];
        #pragma unroll
        for (int o = 0; o < 2; ++o)
            #pragma unroll
            for (int j = 0; j < 6; ++j) acc[o][j] = 0.f;

        for (int cih = 0; cih < 2; ++cih) {
            const int ci0 = half*32 + cih*16;
            __syncthreads();
            for (int u = tid; u < 16*5*28; u += 256) {
                int ci = u / 140, rem = u % 140, rr = rem / 28, k = rem % 28;
                int row = row0 + rr;
                float4 v = {0.f,0.f,0.f,0.f};
                if (row >= 0 && k >= 2 && k <= 25)
                    v = *(const float4*)&xin[((b*64 + ci0 + ci)*96 + row)*96 + 4*k - 8];
                *(float4*)&xs[ci][rr][4*k] = v;
            }
            for (int u = tid; u < 1152; u += 256) {
                int c2 = u / 36, f = u % 36;
                float4 wv = *(const float4*)&wgt[c2*576 + ci0*9 + 4*f];
                int lin = 4*f;
                wsm[(lin  )/9][(lin  )%9][c2] = wv.x;
                wsm[(lin+1)/9][(lin+1)%9][c2] = wv.y;
                wsm[(lin+2)/9][(lin+2)%9][c2] = wv.z;
                wsm[(lin+3)/9][(lin+3)%9][c2] = wv.w;
            }
            __syncthreads();

            for (int ci = 0; ci < 16; ++ci) {
                float w9[9];
                #pragma unroll
                for (int kk = 0; kk < 9; ++kk) w9[kk] = wsm[ci][kk][co];
                #pragma unroll
                for (int rr = 0; rr < 5; ++rr) {
                    const float4* xr = (const float4*)&xs[ci][rr][12*g + 4];
                    float4 t0 = xr[0], t1 = xr[1], t2 = xr[2], t3 = xr[3];
                    float xv[16] = {t0.x,t0.y,t0.z,t0.w, t1.x,t1.y,t1.z,t1.w,
                                    t2.x,t2.y,t2.z,t2.w, t3.x,t3.y,t3.z,t3.w};
                    if (rr <= 2) {
                        #pragma unroll
                        for (int j = 0; j < 6; ++j)
                            #pragma unroll
                            for (int kw = 0; kw < 3; ++kw)
                                acc[0][j] += w9[rr*3+kw] * xv[3 + 2*j + kw];
                    }
                    if (rr >= 2) {
                        #pragma unroll
                        for (int j = 0; j < 6; ++j)
                            #pragma unroll
                            for (int kw = 0; kw < 3; ++kw)
                                acc[1][j] += w9[(rr-2)*3+kw] * xv[3 + 2*j + kw];
                    }
                }
            }
        }
        const int brn = cz - 1;
        float* Pb = Pphi + (size_t)(((half*2 + brn)*4 + b)*32 + co)*N2;
        #pragma unroll
        for (int o = 0; o < 2; ++o)
            #pragma unroll
            for (int j = 0; j < 6; ++j)
                Pb[(2*p + o)*48 + 6*g + j] = acc[o][j];
    }
}

// ---------------------------------------------------------------------------
// K1b: combine the two ci-halves of phi conv, 2x2 maxpool, +bias -> Kp.
// 576 blocks x 256 threads, one pooled output each.
// ---------------------------------------------------------------------------
__global__ __launch_bounds__(256) void phipool_kernel(
    const float* __restrict__ Pphi,
    const float* __restrict__ phi_b, const float* __restrict__ phi_pan_b,
    float* __restrict__ Kp)
{
    const int o = blockIdx.x*256 + threadIdx.x;   // 0..147455 == Kp linear idx
    const int br   = o / 73728;
    const int rem  = o % 73728;
    const int b    = rem / 18432;
    const int rem2 = rem % 18432;
    const int co   = rem2 / 576;
    const int rem3 = rem2 % 576;
    const int pr   = rem3 / 24, pc = rem3 % 24;

    const int h1 = 2*4*32*N2;  // half-1 offset = 589824
    const int base = (((br*4 + b)*32 + co)*48 + 2*pr)*48 + 2*pc;
    float2 a0 = *(const float2*)&Pphi[base];
    float2 a1 = *(const float2*)&Pphi[base + 48];
    float2 c0 = *(const float2*)&Pphi[h1 + base];
    float2 c1 = *(const float2*)&Pphi[h1 + base + 48];
    float v00 = a0.x + c0.x, v01 = a0.y + c0.y;
    float v10 = a1.x + c1.x, v11 = a1.y + c1.y;
    float bv = (br ? phi_pan_b : phi_b)[co];
    Kp[o] = fmaxf(fmaxf(v00, v01), fmaxf(v10, v11)) + bv;
}

// ---------------------------------------------------------------------------
// K2: V = avgpool2(maxpool2(conv1x1(x))). Grid (r4, colhalf, bb) = 384 blocks,
// 384 threads: c = tid&31, sl = tid>>5 (one pooled output each). x staged in
// LDS (shared by all 32 c), weights in padded LDS.
// ---------------------------------------------------------------------------
__global__ __launch_bounds__(384) void gconv_kernel(
    const float* __restrict__ x, const float* __restrict__ x_pan,
    const float* __restrict__ g_w, const float* __restrict__ g_b,
    const float* __restrict__ g_pan_w, const float* __restrict__ g_pan_b,
    float* __restrict__ Vv)
{
    const int r4 = blockIdx.x;      // 0..23
    const int ch = blockIdx.y;      // 0..1
    const int bb = blockIdx.z;      // 0..7
    const int br = bb >> 2, b = bb & 3;
    const float* xin = br ? x_pan : x;
    const float* wg  = br ? g_pan_w : g_w;

    __shared__ __align__(16) float xs[32][4][48];
    __shared__ float wl[64*33];
    const int tid = threadIdx.x;
    for (int u = tid; u < 2048; u += 384) {
        int c2 = u >> 6, ci = u & 63;
        wl[ci*33 + c2] = wg[u];
    }

    const int c  = tid & 31;
    const int sl = tid >> 5;        // 0..11
    float4 ac0 = {0,0,0,0}, ac1 = {0,0,0,0}, ac2 = {0,0,0,0}, ac3 = {0,0,0,0};

    for (int ci0 = 0; ci0 < 64; ci0 += 32) {
        __syncthreads();
        for (int u = tid; u < 32*4*12; u += 384) {
            int ci = u / 48, rem = u % 48, r = rem / 12, k = rem % 12;
            *(float4*)&xs[ci][r][4*k] =
                *(const float4*)&xin[((b*64 + ci0 + ci)*96 + 4*r4 + r)*96 + ch*48 + 4*k];
        }
        __syncthreads();
        for (int ci = 0; ci < 32; ++ci) {
            const float wv = wl[(ci0 + ci)*33 + c];
            float4 x0 = *(const float4*)&xs[ci][0][4*sl];
            float4 x1 = *(const float4*)&xs[ci][1][4*sl];
            float4 x2 = *(const float4*)&xs[ci][2][4*sl];
            float4 x3 = *(const float4*)&xs[ci][3][4*sl];
            ac0.x += wv*x0.x; ac0.y += wv*x0.y; ac0.z += wv*x0.z; ac0.w += wv*x0.w;
            ac1.x += wv*x1.x; ac1.y += wv*x1.y; ac1.z += wv*x1.z; ac1.w += wv*x1.w;
            ac2.x += wv*x2.x; ac2.y += wv*x2.y; ac2.z += wv*x2.z; ac2.w += wv*x2.w;
            ac3.x += wv*x3.x; ac3.y += wv*x3.y; ac3.z += wv*x3.z; ac3.w += wv*x3.w;
        }
    }
    float m00 = fmaxf(fmaxf(ac0.x, ac0.y), fmaxf(ac1.x, ac1.y));
    float m01 = fmaxf(fmaxf(ac0.z, ac0.w), fmaxf(ac1.z, ac1.w));
    float m10 = fmaxf(fmaxf(ac2.x, ac2.y), fmaxf(ac3.x, ac3.y));
    float m11 = fmaxf(fmaxf(ac2.z, ac2.w), fmaxf(ac3.z, ac3.w));
    float bv = (br ? g_pan_b : g_b)[c];
    Vv[(bb*32 + c)*576 + r4*24 + ch*12 + sl] = 0.25f*(m00+m01+m10+m11) + bv;
}

// ---------------------------------------------------------------------------
// K3: attention on the distinct grid. Scores kept in REGISTERS (36/thread),
// ks-reduction via shfl_xor(16,32) + small LDS stash. LDS ~9.7 KB.
// Block (qt, bb): 16 q x 576 k. thread: ql = tid&15, ks = tid>>4.
// ---------------------------------------------------------------------------
__global__ __launch_bounds__(256, 4) void attn_kernel(
    const float* __restrict__ T, const float* __restrict__ Kp,
    const float* __restrict__ Vv, float* __restrict__ Y)
{
    const int qt = blockIdx.x;      // 0..143
    const int bb = blockIdx.y;      // 0..7
    const int b  = bb & 3;

    __shared__ float mbuf[64];            // [w*16+ql]
    __shared__ float zbuf[64];
    __shared__ float avbuf[4*16*33];      // [w*16+ql][c], pad 33

    const int tid  = threadIdx.x;
    const int ql   = tid & 15;
    const int ks   = tid >> 4;            // 0..15
    const int q    = qt*16 + ql;
    const int lane = tid & 63;
    const int w    = tid >> 6;

    // Q: 8 coalesced float4 from T[b][q][*]
    float qv[32];
    const float4* Tq = (const float4*)(T + (size_t)(b*N2 + q)*32);
    #pragma unroll
    for (int i = 0; i < 8; ++i) {
        float4 t = Tq[i];
        qv[4*i] = t.x; qv[4*i+1] = t.y; qv[4*i+2] = t.z; qv[4*i+3] = t.w;
    }

    const float* Kb = Kp + (size_t)bb*32*576;
    const float* Vb = Vv + (size_t)bb*32*576;

    // pass 1: 36 scores in registers
    float sc[36];
    float m = -1e30f;
    #pragma unroll
    for (int jj = 0; jj < 9; ++jj) {
        const int k0 = ks*36 + 4*jj;
        float s0 = 0.f, s1 = 0.f, s2 = 0.f, s3 = 0.f;
        #pragma unroll
        for (int c2 = 0; c2 < 32; ++c2) {
            float4 kv = *(const float4*)&Kb[c2*576 + k0];
            s0 += qv[c2]*kv.x; s1 += qv[c2]*kv.y; s2 += qv[c2]*kv.z; s3 += qv[c2]*kv.w;
        }
        sc[4*jj] = s0; sc[4*jj+1] = s1; sc[4*jj+2] = s2; sc[4*jj+3] = s3;
        m = fmaxf(m, fmaxf(fmaxf(s0, s1), fmaxf(s2, s3)));
    }
    // global max: intra-wave over ks bits, then cross-wave
    m = fmaxf(m, __shfl_xor(m, 16));
    m = fmaxf(m, __shfl_xor(m, 32));
    if (lane < 16) mbuf[w*16 + ql] = m;
    __syncthreads();
    const float M = fmaxf(fmaxf(mbuf[ql], mbuf[16+ql]),
                          fmaxf(mbuf[32+ql], mbuf[48+ql]));

    // pass 2: exp + AV partials
    float av[32];
    #pragma unroll
    for (int c2 = 0; c2 < 32; ++c2) av[c2] = 0.f;
    float zp = 0.f;
    #pragma unroll
    for (int jj = 0; jj < 9; ++jj) {
        const int k0 = ks*36 + 4*jj;
        float p0 = __expf(sc[4*jj]   - M);
        float p1 = __expf(sc[4*jj+1] - M);
        float p2 = __expf(sc[4*jj+2] - M);
        float p3 = __expf(sc[4*jj+3] - M);
        zp += (p0 + p1) + (p2 + p3);
        #pragma unroll
        for (int c2 = 0; c2 < 32; ++c2) {
            float4 vv = *(const float4*)&Vb[c2*576 + k0];
            av[c2] += p0*vv.x + p1*vv.y + p2*vv.z + p3*vv.w;
        }
    }
    // intra-wave reduce over the 4 ks in this wave
    zp += __shfl_xor(zp, 16); zp += __shfl_xor(zp, 32);
    #pragma unroll
    for (int c2 = 0; c2 < 32; ++c2) {
        av[c2] += __shfl_xor(av[c2], 16);
        av[c2] += __shfl_xor(av[c2], 32);
    }
    if (lane < 16) {
        #pragma unroll
        for (int c2 = 0; c2 < 32; ++c2) avbuf[(w*16 + ql)*33 + c2] = av[c2];
        zbuf[w*16 + ql] = zp;
    }
    __syncthreads();

    // final: thread (ql, ks) -> channels 2ks, 2ks+1
    const float Z = zbuf[ql] + zbuf[16+ql] + zbuf[32+ql] + zbuf[48+ql];
    const float inv = 1.0f / Z;
    float* Yb = Y + (size_t)bb*32*N2;
    #pragma unroll
    for (int cc = 0; cc < 2; ++cc) {
        const int c2 = 2*ks + cc;
        float s = avbuf[ql*33 + c2] + avbuf[(16+ql)*33 + c2]
                + avbuf[(32+ql)*33 + c2] + avbuf[(48+ql)*33 + c2];
        Yb[c2*N2 + q] = s * inv;
    }
}

// ---------------------------------------------------------------------------
// K4a: 1x1 W conv -> z (distinct grid) + per-(og,b) partial sum / sumsq.
// Grid (og 0..127, b 0..3) = 512 blocks, 192 threads (3 float4 groups each).
// ---------------------------------------------------------------------------
__global__ __launch_bounds__(192) void wconv_kernel(
    const float* __restrict__ Y,
    const float* __restrict__ W_w, const float* __restrict__ W_b,
    const float* __restrict__ Wp_w, const float* __restrict__ Wp_b,
    float* __restrict__ zbuf, float* __restrict__ Psum, float* __restrict__ Psq)
{
    const int og = blockIdx.x, b = blockIdx.y;
    const int br = og >> 6, o = og & 63;
    const float* Ww = br ? Wp_w : W_w;
    const float bias = (br ? Wp_b : W_b)[o];
    const float* yb = Y + (size_t)(br*4 + b)*32*N2;

    float wreg[32];
    #pragma unroll
    for (int c2 = 0; c2 < 32; ++c2) wreg[c2] = Ww[o*32 + c2];

    const int tid = threadIdx.x;
    float ps = 0.f, pq = 0.f;
    float* zb = zbuf + (size_t)(og*4 + b)*N2;
    #pragma unroll
    for (int i = 0; i < 3; ++i) {
        const int g = tid + 192*i;           // 0..575
        float4 a = {bias, bias, bias, bias};
        #pragma unroll
        for (int c2 = 0; c2 < 32; ++c2) {
            float4 yv = *(const float4*)&yb[c2*N2 + 4*g];
            a.x += wreg[c2]*yv.x; a.y += wreg[c2]*yv.y;
            a.z += wreg[c2]*yv.z; a.w += wreg[c2]*yv.w;
        }
        *(float4*)&zb[4*g] = a;
        ps += (a.x + a.y) + (a.z + a.w);
        pq += (a.x*a.x + a.y*a.y) + (a.z*a.z + a.w*a.w);
    }
    #pragma unroll
    for (int d = 1; d < 64; d <<= 1) {
        ps += __shfl_xor(ps, d);
        pq += __shfl_xor(pq, d);
    }
    __shared__ float sb[3], qb[3];
    const int lane = tid & 63, w = tid >> 6;
    if (lane == 0) { sb[w] = ps; qb[w] = pq; }
    __syncthreads();
    if (tid == 0) {
        Psum[og*4 + b] = sb[0] + sb[1] + sb[2];
        Psq[og*4 + b]  = qb[0] + qb[1] + qb[2];
    }
}

// ---------------------------------------------------------------------------
// K4c: BN (stats from partials; var = E[z^2]-mean^2) + 2x2 nearest upsample.
// Grid (og, b) = 512 blocks, 576 threads (one float4 group each).
// ---------------------------------------------------------------------------
__global__ __launch_bounds__(576) void bnup_kernel(
    const float* __restrict__ zbuf,
    const float* __restrict__ Psum, const float* __restrict__ Psq,
    const float* __restrict__ W_gamma, const float* __restrict__ W_beta,
    const float* __restrict__ Wp_gamma, const float* __restrict__ Wp_beta,
    float* __restrict__ out)
{
    const int og = blockIdx.x, b = blockIdx.y;
    const int br = og >> 6, o = og & 63;
    const float s  = Psum[og*4] + Psum[og*4+1] + Psum[og*4+2] + Psum[og*4+3];
    const float qq = Psq[og*4]  + Psq[og*4+1]  + Psq[og*4+2]  + Psq[og*4+3];
    const float mean = s * (1.0f/9216.0f);
    const float var  = qq * (1.0f/9216.0f) - mean*mean;
    const float gamma = (br ? Wp_gamma : W_gamma)[o];
    const float beta  = (br ? Wp_beta  : W_beta)[o];
    const float scale = gamma * rsqrtf(var + 1e-5f);
    const float shift = beta - mean*scale;

    const int t = threadIdx.x;           // 0..575
    float4 a = *(const float4*)&zbuf[(size_t)(og*4 + b)*N2 + 4*t];
    const int r = t / 12, cs = t % 12;
    float v0 = a.x*scale + shift, v1 = a.y*scale + shift;
    float v2 = a.z*scale + shift, v3 = a.w*scale + shift;
    float4 lo = {v0, v0, v1, v1};
    float4 hi = {v2, v2, v3, v3};
    float* ob = out + ((size_t)(b*128 + og)*96 + 2*r)*96 + 8*cs;
    *(float4*)(ob)      = lo;
    *(float4*)(ob + 4)  = hi;
    *(float4*)(ob + 96) = lo;
    *(float4*)(ob + 100)= hi;
}

// ---------------------------------------------------------------------------
extern "C" void kernel_launch(void* const* d_in, const int* in_sizes, int n_in,
                              void* d_out, int out_size, void* d_ws, size_t ws_size,
                              hipStream_t stream) {
    (void)in_sizes; (void)n_in; (void)out_size; (void)ws_size;
    const float* x         = (const float*)d_in[0];
    const float* x_pan     = (const float*)d_in[1];
    const float* g_w       = (const float*)d_in[2];
    const float* g_b       = (const float*)d_in[3];
    const float* g_pan_w   = (const float*)d_in[4];
    const float* g_pan_b   = (const float*)d_in[5];
    const float* theta_w   = (const float*)d_in[6];
    const float* theta_b   = (const float*)d_in[7];
    const float* phi_w     = (const float*)d_in[8];
    const float* phi_b     = (const float*)d_in[9];
    const float* phi_pan_w = (const float*)d_in[10];
    const float* phi_pan_b = (const float*)d_in[11];
    const float* W_w       = (const float*)d_in[12];
    const float* W_b       = (const float*)d_in[13];
    const float* W_gamma   = (const float*)d_in[14];
    const float* W_beta    = (const float*)d_in[15];
    const float* Wp_w      = (const float*)d_in[16];
    const float* Wp_b      = (const float*)d_in[17];
    const float* Wp_gamma  = (const float*)d_in[18];
    const float* Wp_beta   = (const float*)d_in[19];

    float* out = (float*)d_out;
    float* ws  = (float*)d_ws;

    // workspace layout (floats), total 2,360,320 fl = 9.44 MB
    float* T    = ws;                   // [4][2304][32]        = 294912
    float* Kp   = T  + 294912;          // [8][32][576]         = 147456
    float* Vv   = Kp + 147456;          // [8][32][576]         = 147456
    float* Y    = Vv + 147456;          // [8][32][2304]        = 589824
    float* Pphi = Y  + 589824;          // [2][2][4][32][2304]  = 1179648
    float* zbuf = Pphi;                 // reuse (Pphi dead after K1b)
    float* Psum = Pphi + 1179648;       // 512
    float* Psq  = Psum + 512;           // 512

    conv3x3_kernel<<<dim3(48, 4, 3), 256, 0, stream>>>(
        x, x_pan, theta_w, theta_b, phi_w, phi_pan_w, T, Pphi);
    phipool_kernel<<<dim3(576), 256, 0, stream>>>(Pphi, phi_b, phi_pan_b, Kp);
    gconv_kernel<<<dim3(24, 2, 8), 384, 0, stream>>>(
        x, x_pan, g_w, g_b, g_pan_w, g_pan_b, Vv);
    attn_kernel<<<dim3(144, 8), 256, 0, stream>>>(T, Kp, Vv, Y);
    wconv_kernel<<<dim3(128, 4), 192, 0, stream>>>(
        Y, W_w, W_b, Wp_w, Wp_b, zbuf, Psum, Psq);
    bnup_kernel<<<dim3(128, 4), 576, 0, stream>>>(
        zbuf, Psum, Psq, W_gamma, W_beta, Wp_gamma, Wp_beta, out);
}

// Round 3
// 441.084 us; speedup vs baseline: 1.4775x; 1.4775x over previous
//
#include <hip/hip_runtime.h>
#include <math.h>

#define BB   4
#define CIN  64
#define CMID 32
#define HS   96
#define WS   96
#define H2   48
#define W2   48
#define H4   24
#define W4   24
#define N2   (H2*W2)   // 2304 distinct queries
#define M4   (H4*W4)   // 576 distinct keys

// ---------------------------------------------------------------------------
// K0: zero the BN-stat accumulators (ws is re-poisoned 0xAA every call).
// ---------------------------------------------------------------------------
__global__ __launch_bounds__(256) void zero_kernel(float* __restrict__ p)
{
    p[threadIdx.x] = 0.f;   // 256 floats: Psum[128] + Psq[128]
}

// ---------------------------------------------------------------------------
// K1: 3x3 stride-2 pad-1 convs, ALL uniform blocks.
// Block: bx = p*2+half (p = out-row pair, half = 32-ci half), b, cz.
// 128 threads: c16 = tid&15 (co = c16, c16+16), g = tid>>4 (6 cols).
// Thread tile: 2 co x 2 out rows x 6 cols. 2 chunks of 16 ci.
//  cz=0: theta partial -> Ptheta[half][b][n][32c]   (bias added in attn)
//  cz=1,2: phi partial -> Pphi[half][brn][b][c][n]  (bias added in phipool)
// ---------------------------------------------------------------------------
__global__ __launch_bounds__(128) void conv3x3_kernel(
    const float* __restrict__ x, const float* __restrict__ x_pan,
    const float* __restrict__ theta_w, const float* __restrict__ phi_w,
    const float* __restrict__ phi_pan_w,
    float* __restrict__ Ptheta, float* __restrict__ Pphi)
{
    const int bx = blockIdx.x;   // 0..47
    const int b  = blockIdx.y;
    const int cz = blockIdx.z;

    __shared__ __align__(16) float xs[16][5][104];   // 33.3 KB
    __shared__ float wsm[16][9][32];                 // 18.4 KB

    const int tid = threadIdx.x;
    const int c16 = tid & 15;
    const int g   = tid >> 4;        // 0..7

    const float* xin = (cz == 2) ? x_pan : x;
    const float* wgt = (cz == 0) ? theta_w : (cz == 1 ? phi_w : phi_pan_w);

    const int p    = bx >> 1;
    const int half = bx & 1;
    const int row0 = 4*p - 1;

    float acc[2][2][6];              // [co sel][out row][col]
    #pragma unroll
    for (int u = 0; u < 2; ++u)
        #pragma unroll
        for (int o = 0; o < 2; ++o)
            #pragma unroll
            for (int j = 0; j < 6; ++j) acc[u][o][j] = 0.f;

    for (int chunk = 0; chunk < 2; ++chunk) {
        const int ci0 = half*32 + chunk*16;
        __syncthreads();
        // stage x: 16 ci x 5 rows x 26 float4 (cols -8..95; k<2 are zero pads)
        for (int u = tid; u < 16*5*26; u += 128) {
            int ci = u / 130, rem = u % 130, rr = rem / 26, k = rem % 26;
            int row = row0 + rr;
            float4 v = {0.f,0.f,0.f,0.f};
            if (row >= 0 && row < HS && k >= 2)
                v = *(const float4*)&xin[((b*CIN + ci0 + ci)*HS + row)*WS + 4*k - 8];
            *(float4*)&xs[ci][rr][4*k] = v;
        }
        // stage weights: contiguous float4 per co, scatter to [ci][kk][co]
        for (int u = tid; u < 1152; u += 128) {
            int c2 = u / 36, f = u % 36;
            float4 wv = *(const float4*)&wgt[c2*576 + ci0*9 + 4*f];
            int lin = 4*f;
            wsm[(lin  )/9][(lin  )%9][c2] = wv.x;
            wsm[(lin+1)/9][(lin+1)%9][c2] = wv.y;
            wsm[(lin+2)/9][(lin+2)%9][c2] = wv.z;
            wsm[(lin+3)/9][(lin+3)%9][c2] = wv.w;
        }
        __syncthreads();

        for (int ci = 0; ci < 16; ++ci) {
            float w9a[9], w9b[9];
            #pragma unroll
            for (int kk = 0; kk < 9; ++kk) {
                w9a[kk] = wsm[ci][kk][c16];
                w9b[kk] = wsm[ci][kk][c16 + 16];
            }
            #pragma unroll
            for (int rr = 0; rr < 5; ++rr) {
                const float4* xr = (const float4*)&xs[ci][rr][12*g + 4];
                float4 t0 = xr[0], t1 = xr[1], t2 = xr[2], t3 = xr[3];
                float xv[16] = {t0.x,t0.y,t0.z,t0.w, t1.x,t1.y,t1.z,t1.w,
                                t2.x,t2.y,t2.z,t2.w, t3.x,t3.y,t3.z,t3.w};
                if (rr <= 2) {
                    #pragma unroll
                    for (int j = 0; j < 6; ++j)
                        #pragma unroll
                        for (int kw = 0; kw < 3; ++kw) {
                            float xvv = xv[3 + 2*j + kw];
                            acc[0][0][j] += w9a[rr*3+kw] * xvv;
                            acc[1][0][j] += w9b[rr*3+kw] * xvv;
                        }
                }
                if (rr >= 2) {
                    #pragma unroll
                    for (int j = 0; j < 6; ++j)
                        #pragma unroll
                        for (int kw = 0; kw < 3; ++kw) {
                            float xvv = xv[3 + 2*j + kw];
                            acc[0][1][j] += w9a[(rr-2)*3+kw] * xvv;
                            acc[1][1][j] += w9b[(rr-2)*3+kw] * xvv;
                        }
                }
            }
        }
    }

    if (cz == 0) {
        #pragma unroll
        for (int u = 0; u < 2; ++u)
            #pragma unroll
            for (int o = 0; o < 2; ++o)
                #pragma unroll
                for (int j = 0; j < 6; ++j) {
                    int n = (2*p + o)*48 + 6*g + j;
                    Ptheta[((size_t)(half*4 + b)*N2 + n)*32 + c16 + 16*u] = acc[u][o][j];
                }
    } else {
        const int brn = cz - 1;
        #pragma unroll
        for (int u = 0; u < 2; ++u) {
            float* Pb = Pphi + (size_t)(((half*2 + brn)*4 + b)*32 + c16 + 16*u)*N2;
            #pragma unroll
            for (int o = 0; o < 2; ++o)
                #pragma unroll
                for (int j = 0; j < 6; ++j)
                    Pb[(2*p + o)*48 + 6*g + j] = acc[u][o][j];
        }
    }
}

// ---------------------------------------------------------------------------
// K1b: combine the two ci-halves of phi conv, 2x2 maxpool, +bias.
// Output Kp in [bb][k][c] layout (key-major for attn).
// ---------------------------------------------------------------------------
__global__ __launch_bounds__(256) void phipool_kernel(
    const float* __restrict__ Pphi,
    const float* __restrict__ phi_b, const float* __restrict__ phi_pan_b,
    float* __restrict__ Kp)
{
    const int o = blockIdx.x*256 + threadIdx.x;   // linear over [br][b][co][k]
    const int br   = o / 73728;
    const int rem  = o % 73728;
    const int b    = rem / 18432;
    const int rem2 = rem % 18432;
    const int co   = rem2 / 576;
    const int k    = rem2 % 576;
    const int pr   = k / 24, pc = k % 24;

    const int h1 = 2*4*32*N2;
    const int base = (((br*4 + b)*32 + co)*48 + 2*pr)*48 + 2*pc;
    float2 a0 = *(const float2*)&Pphi[base];
    float2 a1 = *(const float2*)&Pphi[base + 48];
    float2 c0 = *(const float2*)&Pphi[h1 + base];
    float2 c1 = *(const float2*)&Pphi[h1 + base + 48];
    float v00 = a0.x + c0.x, v01 = a0.y + c0.y;
    float v10 = a1.x + c1.x, v11 = a1.y + c1.y;
    float bv = (br ? phi_pan_b : phi_b)[co];
    Kp[((size_t)(br*4 + b)*576 + k)*32 + co] =
        fmaxf(fmaxf(v00, v01), fmaxf(v10, v11)) + bv;
}

// ---------------------------------------------------------------------------
// K2: V = avgpool2(maxpool2(conv1x1(x))), output [bb][k][c].
// ---------------------------------------------------------------------------
__global__ __launch_bounds__(384) void gconv_kernel(
    const float* __restrict__ x, const float* __restrict__ x_pan,
    const float* __restrict__ g_w, const float* __restrict__ g_b,
    const float* __restrict__ g_pan_w, const float* __restrict__ g_pan_b,
    float* __restrict__ Vv)
{
    const int r4 = blockIdx.x;      // 0..23
    const int ch = blockIdx.y;      // 0..1
    const int bb = blockIdx.z;      // 0..7
    const int br = bb >> 2, b = bb & 3;
    const float* xin = br ? x_pan : x;
    const float* wg  = br ? g_pan_w : g_w;

    __shared__ __align__(16) float xs[32][4][48];
    __shared__ float wl[64*33];
    const int tid = threadIdx.x;
    for (int u = tid; u < 2048; u += 384) {
        int c2 = u >> 6, ci = u & 63;
        wl[ci*33 + c2] = wg[u];
    }

    const int c  = tid & 31;
    const int sl = tid >> 5;        // 0..11
    float4 ac0 = {0,0,0,0}, ac1 = {0,0,0,0}, ac2 = {0,0,0,0}, ac3 = {0,0,0,0};

    for (int ci0 = 0; ci0 < 64; ci0 += 32) {
        __syncthreads();
        for (int u = tid; u < 32*4*12; u += 384) {
            int ci = u / 48, rem = u % 48, r = rem / 12, k = rem % 12;
            *(float4*)&xs[ci][r][4*k] =
                *(const float4*)&xin[((b*64 + ci0 + ci)*96 + 4*r4 + r)*96 + ch*48 + 4*k];
        }
        __syncthreads();
        for (int ci = 0; ci < 32; ++ci) {
            const float wv = wl[(ci0 + ci)*33 + c];
            float4 x0 = *(const float4*)&xs[ci][0][4*sl];
            float4 x1 = *(const float4*)&xs[ci][1][4*sl];
            float4 x2 = *(const float4*)&xs[ci][2][4*sl];
            float4 x3 = *(const float4*)&xs[ci][3][4*sl];
            ac0.x += wv*x0.x; ac0.y += wv*x0.y; ac0.z += wv*x0.z; ac0.w += wv*x0.w;
            ac1.x += wv*x1.x; ac1.y += wv*x1.y; ac1.z += wv*x1.z; ac1.w += wv*x1.w;
            ac2.x += wv*x2.x; ac2.y += wv*x2.y; ac2.z += wv*x2.z; ac2.w += wv*x2.w;
            ac3.x += wv*x3.x; ac3.y += wv*x3.y; ac3.z += wv*x3.z; ac3.w += wv*x3.w;
        }
    }
    float m00 = fmaxf(fmaxf(ac0.x, ac0.y), fmaxf(ac1.x, ac1.y));
    float m01 = fmaxf(fmaxf(ac0.z, ac0.w), fmaxf(ac1.z, ac1.w));
    float m10 = fmaxf(fmaxf(ac2.x, ac2.y), fmaxf(ac3.x, ac3.y));
    float m11 = fmaxf(fmaxf(ac2.z, ac2.w), fmaxf(ac3.z, ac3.w));
    float bv = (br ? g_pan_b : g_b)[c];
    const int k = r4*24 + ch*12 + sl;
    Vv[((size_t)bb*576 + k)*32 + c] = 0.25f*(m00+m01+m10+m11) + bv;
}

// ---------------------------------------------------------------------------
// K3: attention (two-pass, score recompute, NO score array) + fused W-conv z
// + BN partial stats. Block (qt, bb): 16 q x 576 k. ql = tid&15, ks = tid>>4.
// Q = Ptheta half0 + half1 + theta_b (theta combine fused here).
// ---------------------------------------------------------------------------
__global__ __launch_bounds__(256) void attn_kernel(
    const float* __restrict__ Ptheta, const float* __restrict__ theta_b,
    const float* __restrict__ Kp, const float* __restrict__ Vv,
    const float* __restrict__ W_w, const float* __restrict__ W_b,
    const float* __restrict__ Wp_w, const float* __restrict__ Wp_b,
    float* __restrict__ zbuf, float* __restrict__ Psum, float* __restrict__ Psq)
{
    const int qt = blockIdx.x;      // 0..143
    const int bb = blockIdx.y;      // 0..7
    const int b  = bb & 3;
    const int br = bb >> 2;

    __shared__ float Wl[64*33];           // W [o][c] padded
    __shared__ float Wb_s[64];
    __shared__ float mbuf[64];
    __shared__ float zsb[64];
    __shared__ float avbuf[64*33];        // per-(wave,ql) AV partials
    __shared__ float ybuf[16*33];         // final y [ql][c]

    const int tid  = threadIdx.x;
    const int ql   = tid & 15;
    const int ks   = tid >> 4;            // 0..15
    const int q    = qt*16 + ql;
    const int lane = tid & 63;
    const int w    = tid >> 6;

    // stage W (branch-local)
    const float* Wsrc = br ? Wp_w : W_w;
    for (int u = tid; u < 2048; u += 256)
        Wl[(u >> 5)*33 + (u & 31)] = Wsrc[u];
    if (tid < 64) Wb_s[tid] = (br ? Wp_b : W_b)[tid];

    // Q = P0 + P1 + theta_b
    float qv[32];
    {
        const float4* P0 = (const float4*)(Ptheta + ((size_t)b*N2 + q)*32);
        const float4* P1 = (const float4*)(Ptheta + ((size_t)(4 + b)*N2 + q)*32);
        const float4* TB = (const float4*)theta_b;
        #pragma unroll
        for (int i = 0; i < 8; ++i) {
            float4 a = P0[i], c = P1[i], t = TB[i];
            qv[4*i]   = a.x + c.x + t.x;
            qv[4*i+1] = a.y + c.y + t.y;
            qv[4*i+2] = a.z + c.z + t.z;
            qv[4*i+3] = a.w + c.w + t.w;
        }
    }

    const float* Kb = Kp + (size_t)bb*576*32;
    const float* Vb = Vv + (size_t)bb*576*32;

    // ---- pass 1: max of scores over this thread's 36 keys ----
    float m = -1e30f;
    for (int jj = 0; jj < 9; ++jj) {
        const int k0 = ks*36 + 4*jj;
        float s[4];
        #pragma unroll
        for (int kk = 0; kk < 4; ++kk) {
            const float4* kr = (const float4*)&Kb[(size_t)(k0 + kk)*32];
            float a0 = 0.f, a1 = 0.f;
            #pragma unroll
            for (int c8 = 0; c8 < 8; ++c8) {
                float4 kv = kr[c8];
                a0 += qv[4*c8]*kv.x + qv[4*c8+2]*kv.z;
                a1 += qv[4*c8+1]*kv.y + qv[4*c8+3]*kv.w;
            }
            s[kk] = a0 + a1;
        }
        m = fmaxf(m, fmaxf(fmaxf(s[0], s[1]), fmaxf(s[2], s[3])));
    }
    m = fmaxf(m, __shfl_xor(m, 16));
    m = fmaxf(m, __shfl_xor(m, 32));
    if (lane < 16) mbuf[w*16 + ql] = m;
    __syncthreads();
    const float M = fmaxf(fmaxf(mbuf[ql], mbuf[16+ql]),
                          fmaxf(mbuf[32+ql], mbuf[48+ql]));

    // ---- pass 2: recompute scores, exp, AV accumulate ----
    float av[32];
    #pragma unroll
    for (int c2 = 0; c2 < 32; ++c2) av[c2] = 0.f;
    float z = 0.f;
    for (int jj = 0; jj < 9; ++jj) {
        const int k0 = ks*36 + 4*jj;
        float p[4];
        #pragma unroll
        for (int kk = 0; kk < 4; ++kk) {
            const float4* kr = (const float4*)&Kb[(size_t)(k0 + kk)*32];
            float a0 = 0.f, a1 = 0.f;
            #pragma unroll
            for (int c8 = 0; c8 < 8; ++c8) {
                float4 kv = kr[c8];
                a0 += qv[4*c8]*kv.x + qv[4*c8+2]*kv.z;
                a1 += qv[4*c8+1]*kv.y + qv[4*c8+3]*kv.w;
            }
            p[kk] = __expf(a0 + a1 - M);
            z += p[kk];
        }
        #pragma unroll
        for (int kk = 0; kk < 4; ++kk) {
            const float4* vr = (const float4*)&Vb[(size_t)(k0 + kk)*32];
            #pragma unroll
            for (int c8 = 0; c8 < 8; ++c8) {
                float4 vv = vr[c8];
                av[4*c8]   += p[kk]*vv.x;
                av[4*c8+1] += p[kk]*vv.y;
                av[4*c8+2] += p[kk]*vv.z;
                av[4*c8+3] += p[kk]*vv.w;
            }
        }
    }
    // reduce over the wave's 4 ks slices
    z += __shfl_xor(z, 16); z += __shfl_xor(z, 32);
    #pragma unroll
    for (int c2 = 0; c2 < 32; ++c2) {
        av[c2] += __shfl_xor(av[c2], 16);
        av[c2] += __shfl_xor(av[c2], 32);
    }
    if (lane < 16) {
        #pragma unroll
        for (int c2 = 0; c2 < 32; ++c2) avbuf[(w*16 + ql)*33 + c2] = av[c2];
        zsb[w*16 + ql] = z;
    }
    __syncthreads();

    // final y for channels 2ks, 2ks+1 of query ql -> ybuf
    const float Z = zsb[ql] + zsb[16+ql] + zsb[32+ql] + zsb[48+ql];
    const float inv = 1.0f / Z;
    #pragma unroll
    for (int cc = 0; cc < 2; ++cc) {
        const int c2 = 2*ks + cc;
        float sv = avbuf[ql*33 + c2] + avbuf[(16+ql)*33 + c2]
                 + avbuf[(32+ql)*33 + c2] + avbuf[(48+ql)*33 + c2];
        ybuf[ql*33 + c2] = sv * inv;
    }
    __syncthreads();

    // ---- fused 1x1 W conv + BN partial stats: 4 og per thread ----
    #pragma unroll
    for (int i = 0; i < 4; ++i) {
        const int o  = ks*4 + i;
        const int og = br*64 + o;
        float zv = Wb_s[o];
        #pragma unroll
        for (int c2 = 0; c2 < 32; ++c2)
            zv += Wl[o*33 + c2] * ybuf[ql*33 + c2];
        zbuf[((size_t)og*4 + b)*N2 + q] = zv;
        float s1 = zv, s2 = zv*zv;
        #pragma unroll
        for (int d = 1; d < 16; d <<= 1) {
            s1 += __shfl_xor(s1, d);
            s2 += __shfl_xor(s2, d);
        }
        if (ql == 0) {
            atomicAdd(&Psum[og], s1);
            atomicAdd(&Psq[og],  s2);
        }
    }
}

// ---------------------------------------------------------------------------
// K4: BN (global stats from atomics; var = E[z^2]-mean^2) + 2x2 upsample.
// ---------------------------------------------------------------------------
__global__ __launch_bounds__(576) void bnup_kernel(
    const float* __restrict__ zbuf,
    const float* __restrict__ Psum, const float* __restrict__ Psq,
    const float* __restrict__ W_gamma, const float* __restrict__ W_beta,
    const float* __restrict__ Wp_gamma, const float* __restrict__ Wp_beta,
    float* __restrict__ out)
{
    const int og = blockIdx.x, b = blockIdx.y;
    const int br = og >> 6, o = og & 63;
    const float mean = Psum[og] * (1.0f/9216.0f);
    const float var  = Psq[og] * (1.0f/9216.0f) - mean*mean;
    const float gamma = (br ? Wp_gamma : W_gamma)[o];
    const float beta  = (br ? Wp_beta  : W_beta)[o];
    const float scale = gamma * rsqrtf(var + 1e-5f);
    const float shift = beta - mean*scale;

    const int t = threadIdx.x;           // 0..575
    float4 a = *(const float4*)&zbuf[((size_t)og*4 + b)*N2 + 4*t];
    const int r = t / 12, cs = t % 12;
    float v0 = a.x*scale + shift, v1 = a.y*scale + shift;
    float v2 = a.z*scale + shift, v3 = a.w*scale + shift;
    float4 lo = {v0, v0, v1, v1};
    float4 hi = {v2, v2, v3, v3};
    float* ob = out + ((size_t)(b*128 + og)*96 + 2*r)*96 + 8*cs;
    *(float4*)(ob)       = lo;
    *(float4*)(ob + 4)   = hi;
    *(float4*)(ob + 96)  = lo;
    *(float4*)(ob + 100) = hi;
}

// ---------------------------------------------------------------------------
extern "C" void kernel_launch(void* const* d_in, const int* in_sizes, int n_in,
                              void* d_out, int out_size, void* d_ws, size_t ws_size,
                              hipStream_t stream) {
    (void)in_sizes; (void)n_in; (void)out_size; (void)ws_size;
    const float* x         = (const float*)d_in[0];
    const float* x_pan     = (const float*)d_in[1];
    const float* g_w       = (const float*)d_in[2];
    const float* g_b       = (const float*)d_in[3];
    const float* g_pan_w   = (const float*)d_in[4];
    const float* g_pan_b   = (const float*)d_in[5];
    const float* theta_w   = (const float*)d_in[6];
    const float* theta_b   = (const float*)d_in[7];
    const float* phi_w     = (const float*)d_in[8];
    const float* phi_b     = (const float*)d_in[9];
    const float* phi_pan_w = (const float*)d_in[10];
    const float* phi_pan_b = (const float*)d_in[11];
    const float* W_w       = (const float*)d_in[12];
    const float* W_b       = (const float*)d_in[13];
    const float* W_gamma   = (const float*)d_in[14];
    const float* W_beta    = (const float*)d_in[15];
    const float* Wp_w      = (const float*)d_in[16];
    const float* Wp_b      = (const float*)d_in[17];
    const float* Wp_gamma  = (const float*)d_in[18];
    const float* Wp_beta   = (const float*)d_in[19];

    float* out = (float*)d_out;
    float* ws  = (float*)d_ws;

    // workspace (floats), total 2,064,640 = 8.26 MB
    float* Ptheta = ws;                    // [2][4][2304][32] = 589824
    float* Pphi   = Ptheta + 589824;       // [2][2][4][32][2304] = 1179648
    float* zbuf   = Pphi;                  // alias: [128][4][2304] (Pphi dead)
    float* Kp     = Pphi + 1179648;        // [8][576][32] = 147456
    float* Vv     = Kp + 147456;           // [8][576][32] = 147456
    float* Psum   = Vv + 147456;           // [128]
    float* Psq    = Psum + 128;            // [128]

    zero_kernel<<<dim3(1), 256, 0, stream>>>(Psum);
    conv3x3_kernel<<<dim3(48, 4, 3), 128, 0, stream>>>(
        x, x_pan, theta_w, phi_w, phi_pan_w, Ptheta, Pphi);
    phipool_kernel<<<dim3(576), 256, 0, stream>>>(Pphi, phi_b, phi_pan_b, Kp);
    gconv_kernel<<<dim3(24, 2, 8), 384, 0, stream>>>(
        x, x_pan, g_w, g_b, g_pan_w, g_pan_b, Vv);
    attn_kernel<<<dim3(144, 8), 256, 0, stream>>>(
        Ptheta, theta_b, Kp, Vv, W_w, W_b, Wp_w, Wp_b, zbuf, Psum, Psq);
    bnup_kernel<<<dim3(128, 4), 576, 0, stream>>>(
        zbuf, Psum, Psq, W_gamma, W_beta, Wp_gamma, Wp_beta, out);
}